// Round 2
// baseline (1848.511 us; speedup 1.0000x reference)
//
#include <hip/hip_runtime.h>

#define NNODES 50000
#define NEDGES 800000
#define DD 128

#define TE 64          // rows (edges or nodes) per block tile
#define KT 16          // k-chunk per weight stage
#define AX_S 260       // LDS row stride (words) for A tile: 256 + 4 pad (16B aligned)
#define HS_S 132       // LDS row stride (words) for H tile: 128 + 4 pad
#define AX_WORDS (TE * AX_S)        // 16640
#define WT_WORDS (KT * DD)          // 2048
#define SMEM_WORDS (AX_WORDS + WT_WORDS + TE)  // + scol

// ---------------------------------------------------------------------------
// zero the aggregation buffer (d_out is poisoned 0xAA before every call)
__global__ void zero_kernel(float4* __restrict__ p, int n4) {
    int i = blockIdx.x * blockDim.x + threadIdx.x;
    if (i < n4) p[i] = make_float4(0.f, 0.f, 0.f, 0.f);
}

// ---------------------------------------------------------------------------
// Edge kernel: messages = (relu([x[row]|x[col]] @ W1 + b1)) @ W2 + b2
// then atomicAdd into agg[col].  agg aliases d_out (node kernel fixes it up).
__global__ __launch_bounds__(256, 2)
void edge_kernel(const float* __restrict__ x,
                 const int* __restrict__ ei,          // int32 [2][E]
                 const float* __restrict__ W1, const float* __restrict__ b1,
                 const float* __restrict__ W2, const float* __restrict__ b2,
                 float* agg) {
    __shared__ float smem[SMEM_WORDS];
    float* Ax = smem;                 // [64][AX_S] input tile (row-major)
    float* Hs = smem;                 // [64][HS_S] hidden tile, overlays Ax
    float* Wt = smem + AX_WORDS;      // [KT][128] weight chunk
    int* scol = (int*)(smem + AX_WORDS + WT_WORDS);

    const int t = threadIdx.x;
    const int base = blockIdx.x * TE;

    // ---- stage gathered inputs: Ax[e][0:128]=x[row[e]], Ax[e][128:256]=x[col[e]]
    {
        const int e = t & 63;
        const int q = t >> 6;                       // 0..3
        const int r = ei[base + e];
        const int c = ei[NEDGES + base + e];
        if (t < 64) scol[t] = c;
        const float* srcr = x + (size_t)r * DD;
        const float* srcc = x + (size_t)c * DD;
#pragma unroll
        for (int ci = 0; ci < 16; ++ci) {
            const int k4 = ci * 4 + q;              // 0..63 (float4 index in row)
            float4 v;
            if (k4 < 32) v = *(const float4*)(srcr + k4 * 4);
            else         v = *(const float4*)(srcc + (k4 - 32) * 4);
            *(float4*)(Ax + e * AX_S + k4 * 4) = v;
        }
    }

    const int jg = t & 31;
    const int eg = t >> 5;          // 0..7 ; per-wave eg spans only 2 values
    const int j0 = jg * 4;

    const float4 b1v = *(const float4*)(b1 + j0);
    const float4 b2v = *(const float4*)(b2 + j0);

    float acc[8][4];
#pragma unroll
    for (int i = 0; i < 8; ++i)
        acc[i][0] = acc[i][1] = acc[i][2] = acc[i][3] = 0.f;

    // ---- GEMM1: [64][256] @ W1[256][128]
    for (int kb = 0; kb < 256 / KT; ++kb) {
        __syncthreads();
        {   // stage W1 rows [kb*KT, kb*KT+KT)
            const float* src = W1 + kb * KT * DD;
#pragma unroll
            for (int u = 0; u < 2; ++u) {
                const int f4i = u * 256 + t;        // 0..511
                *(float4*)(Wt + f4i * 4) = *(const float4*)(src + f4i * 4);
            }
        }
        __syncthreads();
        float4 Bc[KT];
#pragma unroll
        for (int kk = 0; kk < KT; ++kk)
            Bc[kk] = *(const float4*)(Wt + kk * DD + j0);
#pragma unroll
        for (int i = 0; i < 8; ++i) {
            const float* arow = Ax + (i * 8 + eg) * AX_S + kb * KT;
            float a[KT];
#pragma unroll
            for (int kc = 0; kc < KT / 4; ++kc) {
                const float4 av = *(const float4*)(arow + kc * 4);
                a[kc * 4 + 0] = av.x; a[kc * 4 + 1] = av.y;
                a[kc * 4 + 2] = av.z; a[kc * 4 + 3] = av.w;
            }
#pragma unroll
            for (int kk = 0; kk < KT; ++kk) {
                acc[i][0] = fmaf(a[kk], Bc[kk].x, acc[i][0]);
                acc[i][1] = fmaf(a[kk], Bc[kk].y, acc[i][1]);
                acc[i][2] = fmaf(a[kk], Bc[kk].z, acc[i][2]);
                acc[i][3] = fmaf(a[kk], Bc[kk].w, acc[i][3]);
            }
        }
    }
    __syncthreads();   // everyone done reading Ax before Hs overlays it

    // ---- bias + relu -> Hs
#pragma unroll
    for (int i = 0; i < 8; ++i) {
        float4 h;
        h.x = fmaxf(acc[i][0] + b1v.x, 0.f);
        h.y = fmaxf(acc[i][1] + b1v.y, 0.f);
        h.z = fmaxf(acc[i][2] + b1v.z, 0.f);
        h.w = fmaxf(acc[i][3] + b1v.w, 0.f);
        *(float4*)(Hs + (i * 8 + eg) * HS_S + j0) = h;
        acc[i][0] = acc[i][1] = acc[i][2] = acc[i][3] = 0.f;
    }

    // ---- GEMM2: [64][128] @ W2[128][128]
    for (int kb = 0; kb < DD / KT; ++kb) {
        __syncthreads();
        {
            const float* src = W2 + kb * KT * DD;
#pragma unroll
            for (int u = 0; u < 2; ++u) {
                const int f4i = u * 256 + t;
                *(float4*)(Wt + f4i * 4) = *(const float4*)(src + f4i * 4);
            }
        }
        __syncthreads();
        float4 Bc[KT];
#pragma unroll
        for (int kk = 0; kk < KT; ++kk)
            Bc[kk] = *(const float4*)(Wt + kk * DD + j0);
#pragma unroll
        for (int i = 0; i < 8; ++i) {
            const float* arow = Hs + (i * 8 + eg) * HS_S + kb * KT;
            float a[KT];
#pragma unroll
            for (int kc = 0; kc < KT / 4; ++kc) {
                const float4 av = *(const float4*)(arow + kc * 4);
                a[kc * 4 + 0] = av.x; a[kc * 4 + 1] = av.y;
                a[kc * 4 + 2] = av.z; a[kc * 4 + 3] = av.w;
            }
#pragma unroll
            for (int kk = 0; kk < KT; ++kk) {
                acc[i][0] = fmaf(a[kk], Bc[kk].x, acc[i][0]);
                acc[i][1] = fmaf(a[kk], Bc[kk].y, acc[i][1]);
                acc[i][2] = fmaf(a[kk], Bc[kk].z, acc[i][2]);
                acc[i][3] = fmaf(a[kk], Bc[kk].w, acc[i][3]);
            }
        }
    }

    // ---- scatter-add messages to agg[col]
#pragma unroll
    for (int i = 0; i < 8; ++i) {
        const int c = scol[i * 8 + eg];
        float* dst = agg + (size_t)c * DD + j0;
        atomicAdd(dst + 0, acc[i][0] + b2v.x);
        atomicAdd(dst + 1, acc[i][1] + b2v.y);
        atomicAdd(dst + 2, acc[i][2] + b2v.z);
        atomicAdd(dst + 3, acc[i][3] + b2v.w);
    }
}

// ---------------------------------------------------------------------------
// Node kernel: out = relu( relu([x|agg] @ U1 + c1) @ U2 + c2 )
// aggout is BOTH the aggregation input and the final output (d_out).
// Safe: each block reads only its own 64 rows (staging, before any write)
// and writes only those same rows at the end.
__global__ __launch_bounds__(256, 2)
void node_kernel(const float* __restrict__ x,
                 float* aggout,
                 const float* __restrict__ U1, const float* __restrict__ c1,
                 const float* __restrict__ U2, const float* __restrict__ c2) {
    __shared__ float smem[SMEM_WORDS];
    float* Ax = smem;
    float* Hs = smem;
    float* Wt = smem + AX_WORDS;

    const int t = threadIdx.x;
    const int base = blockIdx.x * TE;

    // ---- stage [x[n] | agg[n]]
    {
        const int e = t & 63;
        const int q = t >> 6;
        const int n = base + e;
        const bool valid = n < NNODES;
        const float* s1 = x + (size_t)n * DD;
        const float* s2 = aggout + (size_t)n * DD;
#pragma unroll
        for (int ci = 0; ci < 16; ++ci) {
            const int k4 = ci * 4 + q;
            float4 v = make_float4(0.f, 0.f, 0.f, 0.f);
            if (valid) {
                if (k4 < 32) v = *(const float4*)(s1 + k4 * 4);
                else         v = *(const float4*)(s2 + (k4 - 32) * 4);
            }
            *(float4*)(Ax + e * AX_S + k4 * 4) = v;
        }
    }

    const int jg = t & 31;
    const int eg = t >> 5;
    const int j0 = jg * 4;

    const float4 b1v = *(const float4*)(c1 + j0);
    const float4 b2v = *(const float4*)(c2 + j0);

    float acc[8][4];
#pragma unroll
    for (int i = 0; i < 8; ++i)
        acc[i][0] = acc[i][1] = acc[i][2] = acc[i][3] = 0.f;

    for (int kb = 0; kb < 256 / KT; ++kb) {
        __syncthreads();
        {
            const float* src = U1 + kb * KT * DD;
#pragma unroll
            for (int u = 0; u < 2; ++u) {
                const int f4i = u * 256 + t;
                *(float4*)(Wt + f4i * 4) = *(const float4*)(src + f4i * 4);
            }
        }
        __syncthreads();
        float4 Bc[KT];
#pragma unroll
        for (int kk = 0; kk < KT; ++kk)
            Bc[kk] = *(const float4*)(Wt + kk * DD + j0);
#pragma unroll
        for (int i = 0; i < 8; ++i) {
            const float* arow = Ax + (i * 8 + eg) * AX_S + kb * KT;
            float a[KT];
#pragma unroll
            for (int kc = 0; kc < KT / 4; ++kc) {
                const float4 av = *(const float4*)(arow + kc * 4);
                a[kc * 4 + 0] = av.x; a[kc * 4 + 1] = av.y;
                a[kc * 4 + 2] = av.z; a[kc * 4 + 3] = av.w;
            }
#pragma unroll
            for (int kk = 0; kk < KT; ++kk) {
                acc[i][0] = fmaf(a[kk], Bc[kk].x, acc[i][0]);
                acc[i][1] = fmaf(a[kk], Bc[kk].y, acc[i][1]);
                acc[i][2] = fmaf(a[kk], Bc[kk].z, acc[i][2]);
                acc[i][3] = fmaf(a[kk], Bc[kk].w, acc[i][3]);
            }
        }
    }
    __syncthreads();

#pragma unroll
    for (int i = 0; i < 8; ++i) {
        float4 h;
        h.x = fmaxf(acc[i][0] + b1v.x, 0.f);
        h.y = fmaxf(acc[i][1] + b1v.y, 0.f);
        h.z = fmaxf(acc[i][2] + b1v.z, 0.f);
        h.w = fmaxf(acc[i][3] + b1v.w, 0.f);
        *(float4*)(Hs + (i * 8 + eg) * HS_S + j0) = h;
        acc[i][0] = acc[i][1] = acc[i][2] = acc[i][3] = 0.f;
    }

    for (int kb = 0; kb < DD / KT; ++kb) {
        __syncthreads();
        {
            const float* src = U2 + kb * KT * DD;
#pragma unroll
            for (int u = 0; u < 2; ++u) {
                const int f4i = u * 256 + t;
                *(float4*)(Wt + f4i * 4) = *(const float4*)(src + f4i * 4);
            }
        }
        __syncthreads();
        float4 Bc[KT];
#pragma unroll
        for (int kk = 0; kk < KT; ++kk)
            Bc[kk] = *(const float4*)(Wt + kk * DD + j0);
#pragma unroll
        for (int i = 0; i < 8; ++i) {
            const float* arow = Hs + (i * 8 + eg) * HS_S + kb * KT;
            float a[KT];
#pragma unroll
            for (int kc = 0; kc < KT / 4; ++kc) {
                const float4 av = *(const float4*)(arow + kc * 4);
                a[kc * 4 + 0] = av.x; a[kc * 4 + 1] = av.y;
                a[kc * 4 + 2] = av.z; a[kc * 4 + 3] = av.w;
            }
#pragma unroll
            for (int kk = 0; kk < KT; ++kk) {
                acc[i][0] = fmaf(a[kk], Bc[kk].x, acc[i][0]);
                acc[i][1] = fmaf(a[kk], Bc[kk].y, acc[i][1]);
                acc[i][2] = fmaf(a[kk], Bc[kk].z, acc[i][2]);
                acc[i][3] = fmaf(a[kk], Bc[kk].w, acc[i][3]);
            }
        }
    }

    // ---- final bias + relu, store (overwrites agg rows owned by this block)
#pragma unroll
    for (int i = 0; i < 8; ++i) {
        const int n = base + i * 8 + eg;
        if (n < NNODES) {
            float4 o;
            o.x = fmaxf(acc[i][0] + b2v.x, 0.f);
            o.y = fmaxf(acc[i][1] + b2v.y, 0.f);
            o.z = fmaxf(acc[i][2] + b2v.z, 0.f);
            o.w = fmaxf(acc[i][3] + b2v.w, 0.f);
            *(float4*)(aggout + (size_t)n * DD + j0) = o;
        }
    }
}

// ---------------------------------------------------------------------------
extern "C" void kernel_launch(void* const* d_in, const int* in_sizes, int n_in,
                              void* d_out, int out_size, void* d_ws, size_t ws_size,
                              hipStream_t stream) {
    const float* x   = (const float*)d_in[0];
    const int*   ei  = (const int*)d_in[1];     // harness delivers integers as int32
    const float* mW1 = (const float*)d_in[2];
    const float* mb1 = (const float*)d_in[3];
    const float* mW2 = (const float*)d_in[4];
    const float* mb2 = (const float*)d_in[5];
    const float* uW1 = (const float*)d_in[6];
    const float* ub1 = (const float*)d_in[7];
    const float* uW2 = (const float*)d_in[8];
    const float* ub2 = (const float*)d_in[9];
    float* out = (float*)d_out;   // doubles as the [N][128] aggregation buffer

    const int n4 = NNODES * DD / 4;             // 1.6M float4
    zero_kernel<<<(n4 + 255) / 256, 256, 0, stream>>>((float4*)out, n4);
    edge_kernel<<<NEDGES / TE, 256, 0, stream>>>(x, ei, mW1, mb1, mW2, mb2, out);
    node_kernel<<<(NNODES + TE - 1) / TE, 256, 0, stream>>>(x, out, uW1, ub1,
                                                            uW2, ub2);
}

// Round 3
// 633.095 us; speedup vs baseline: 2.9198x; 2.9198x over previous
//
#include <hip/hip_runtime.h>
#include <stdint.h>

typedef unsigned short ushort_t;

#define NNODES 50000
#define NEDGES 800000
#define DD 128

// ---------------- MFMA frag types (per guide §3: short8 = 8 bf16 = 4 VGPR) ----
typedef short bf16x8 __attribute__((ext_vector_type(8)));
typedef float f32x16 __attribute__((ext_vector_type(16)));

// ---------------- ws layout (bytes) ----------------
#define XH_OFF   0
#define XL_OFF   (NNODES * DD * 2)                 // 12,800,000
#define W1_ELEMS (256 * 128)
#define W2_ELEMS (128 * 128)
#define W1H_OFF  (2 * NNODES * DD * 2)             // 25,600,000
#define W1L_OFF  (W1H_OFF + W1_ELEMS * 2)
#define W2H_OFF  (W1L_OFF + W1_ELEMS * 2)
#define W2L_OFF  (W2H_OFF + W2_ELEMS * 2)
#define WS_NEEDED (size_t)(W2L_OFF + W2_ELEMS * 2)

// ---------------------------------------------------------------------------
__global__ void zero_kernel(float4* __restrict__ p, int n4) {
    int i = blockIdx.x * blockDim.x + threadIdx.x;
    if (i < n4) p[i] = make_float4(0.f, 0.f, 0.f, 0.f);
}

// Split fp32 -> bf16 hi (truncate) + bf16 lo (residual, truncate).
__device__ inline void bf16_split(float f, ushort_t& hi, ushort_t& lo) {
    uint32_t b = __float_as_uint(f);
    uint32_t hb = b & 0xFFFF0000u;
    hi = (ushort_t)(b >> 16);
    float lof = f - __uint_as_float(hb);
    lo = (ushort_t)(__float_as_uint(lof) >> 16);
}

__global__ void pack_x(const float* __restrict__ x,
                       ushort_t* __restrict__ xh, ushort_t* __restrict__ xl) {
    int i = blockIdx.x * blockDim.x + threadIdx.x;
    if (i >= NNODES * DD) return;
    ushort_t h, l;
    bf16_split(x[i], h, l);
    xh[i] = h; xl[i] = l;
}

// Pack W [K][128] into B-fragment order for mfma_32x32x16:
// elem (k, n) -> ktile = k>>4, g = (k>>3)&1, e = k&7 ; flat = ktile*2048 + (g*128+n)*8 + e
__global__ void pack_w(const float* __restrict__ W,
                       ushort_t* __restrict__ wh, ushort_t* __restrict__ wl, int K) {
    int i = blockIdx.x * blockDim.x + threadIdx.x;
    if (i >= K * 128) return;
    int k = i >> 7, n = i & 127;
    int dst = (k >> 4) * 2048 + ((((k >> 3) & 1) * 128 + n) << 3) + (k & 7);
    ushort_t h, l;
    bf16_split(W[i], h, l);
    wh[dst] = h; wl[dst] = l;
}

// ---------------------------------------------------------------------------
// MFMA edge kernel. 128 edges/block, 4 waves; wave w owns edges w*32..w*32+31.
// GEMM1: A[128x256] (gathered bf16 hi/lo from xh/xl) @ W1[256x128]
// GEMM2: relu(H) @ W2, H via 64KB swizzled LDS roundtrip.
// 3-product split per tile: Ah*Bh + Ah*Bl + Al*Bh (fp32 acc).
#define EB 128
// H word index with XOR slot swizzle (row = 512B, 32 slots of 16B)
__device__ inline int hs_idx(int m, int j) {
    return m * 128 + ((((j >> 2) ^ (m & 31)) << 2) | (j & 3));
}

__global__ __launch_bounds__(256, 2)
void edge_mfma(const ushort_t* __restrict__ xh, const ushort_t* __restrict__ xl,
               const ushort_t* __restrict__ w1h, const ushort_t* __restrict__ w1l,
               const ushort_t* __restrict__ w2h, const ushort_t* __restrict__ w2l,
               const int* __restrict__ ei,
               const float* __restrict__ b1, const float* __restrict__ b2,
               float* agg) {
    __shared__ __align__(16) float   Hs[128 * 128];   // 64 KB
    __shared__ __align__(16) ushort_t Wh[2048];       // 4 KB
    __shared__ __align__(16) ushort_t Wl[2048];       // 4 KB

    const int t  = threadIdx.x;
    const int w  = t >> 6;
    const int l  = t & 63;
    const int lh = l >> 5;          // lane half: k-group
    const int ln = l & 31;          // A row within tile / C col
    const int eg = blockIdx.x * EB + w * 32 + ln;

    const int rv = ei[eg];                 // source node (row)
    const int cv = ei[NEDGES + eg];        // dest node (col)

    float bias1[4], bias2[4];
#pragma unroll
    for (int tt = 0; tt < 4; ++tt) {
        bias1[tt] = b1[tt * 32 + ln];
        bias2[tt] = b2[tt * 32 + ln];
    }

    f32x16 acc[4];
#pragma unroll
    for (int tt = 0; tt < 4; ++tt)
#pragma unroll
        for (int q = 0; q < 16; ++q) acc[tt][q] = 0.f;

    // prefetch A for u=0 (k0 = lh*8 < 128 -> row side)
    bf16x8 a_hi_next = *(const bf16x8*)(xh + (size_t)rv * DD + lh * 8);
    bf16x8 a_lo_next = *(const bf16x8*)(xl + (size_t)rv * DD + lh * 8);

    // ---- GEMM1: K = 256, 16 ksteps of 16 ----
    for (int u = 0; u < 16; ++u) {
        __syncthreads();   // W buffer free to overwrite
        *(float4*)(Wh + t * 8) = *(const float4*)(w1h + u * 2048 + t * 8);
        *(float4*)(Wl + t * 8) = *(const float4*)(w1l + u * 2048 + t * 8);
        bf16x8 a_hi = a_hi_next, a_lo = a_lo_next;
        if (u < 15) {
            int kk = (u + 1) * 16 + lh * 8;
            int node = (kk < 128) ? rv : cv;
            int off  = kk & 127;
            a_hi_next = *(const bf16x8*)(xh + (size_t)node * DD + off);
            a_lo_next = *(const bf16x8*)(xl + (size_t)node * DD + off);
        }
        __syncthreads();   // W staged
#pragma unroll
        for (int tt = 0; tt < 4; ++tt) {
            const int boff = (lh * 128 + tt * 32 + ln) * 8;
            bf16x8 bh = *(const bf16x8*)(Wh + boff);
            bf16x8 bl = *(const bf16x8*)(Wl + boff);
            acc[tt] = __builtin_amdgcn_mfma_f32_32x32x16_bf16(a_hi, bh, acc[tt], 0, 0, 0);
            acc[tt] = __builtin_amdgcn_mfma_f32_32x32x16_bf16(a_hi, bl, acc[tt], 0, 0, 0);
            acc[tt] = __builtin_amdgcn_mfma_f32_32x32x16_bf16(a_lo, bh, acc[tt], 0, 0, 0);
        }
    }

    // ---- bias1 + relu -> Hs (each wave writes only its own 32 rows) ----
    __syncthreads();
#pragma unroll
    for (int tt = 0; tt < 4; ++tt) {
#pragma unroll
        for (int r = 0; r < 16; ++r) {
            int mrow = w * 32 + (r & 3) + 8 * (r >> 2) + 4 * lh;   // C-layout row
            int j    = tt * 32 + ln;                               // C-layout col
            Hs[hs_idx(mrow, j)] = fmaxf(acc[tt][r] + bias1[tt], 0.f);
            acc[tt][r] = 0.f;
        }
    }
    __syncthreads();

    // ---- GEMM2: K = 128, 8 ksteps ----
    for (int u = 0; u < 8; ++u) {
        __syncthreads();
        *(float4*)(Wh + t * 8) = *(const float4*)(w2h + u * 2048 + t * 8);
        *(float4*)(Wl + t * 8) = *(const float4*)(w2l + u * 2048 + t * 8);
        __syncthreads();
        // A-frag from Hs: row m = w*32+ln, k = u*16 + lh*8 .. +7
        const int m  = w * 32 + ln;
        const int s0 = u * 4 + lh * 2;            // 16B slot of kk
        float4 f0 = *(const float4*)(Hs + m * 128 + (((s0    ) ^ ln) << 2));
        float4 f1 = *(const float4*)(Hs + m * 128 + (((s0 + 1) ^ ln) << 2));
        float fv[8] = {f0.x, f0.y, f0.z, f0.w, f1.x, f1.y, f1.z, f1.w};
        bf16x8 a_hi, a_lo;
#pragma unroll
        for (int q = 0; q < 8; ++q) {
            ushort_t h, lo16;
            bf16_split(fv[q], h, lo16);
            a_hi[q] = (short)h;
            a_lo[q] = (short)lo16;
        }
#pragma unroll
        for (int tt = 0; tt < 4; ++tt) {
            const int boff = (lh * 128 + tt * 32 + ln) * 8;
            bf16x8 bh = *(const bf16x8*)(Wh + boff);
            bf16x8 bl = *(const bf16x8*)(Wl + boff);
            acc[tt] = __builtin_amdgcn_mfma_f32_32x32x16_bf16(a_hi, bh, acc[tt], 0, 0, 0);
            acc[tt] = __builtin_amdgcn_mfma_f32_32x32x16_bf16(a_hi, bl, acc[tt], 0, 0, 0);
            acc[tt] = __builtin_amdgcn_mfma_f32_32x32x16_bf16(a_lo, bh, acc[tt], 0, 0, 0);
        }
    }

    // ---- scatter: messages -> agg[col]  (col for row mr held by lane mr) ----
    int cn[16];
#pragma unroll
    for (int r = 0; r < 16; ++r) {
        int mr = (r & 3) + 8 * (r >> 2) + 4 * lh;
        cn[r] = __shfl(cv, mr, 64);
    }
#pragma unroll
    for (int tt = 0; tt < 4; ++tt) {
#pragma unroll
        for (int r = 0; r < 16; ++r) {
            atomicAdd(agg + (size_t)cn[r] * DD + tt * 32 + ln,
                      acc[tt][r] + bias2[tt]);
        }
    }
}

// ---------------------------------------------------------------------------
// Fallback fp32 edge kernel (Round-2 proven path, used if ws too small)
#define TE 64
#define KT 16
#define AX_S 260
#define HS_S 132
#define AX_WORDS (TE * AX_S)
#define WT_WORDS (KT * DD)
#define SMEM_WORDS (AX_WORDS + WT_WORDS + TE)

__global__ __launch_bounds__(256, 2)
void edge_kernel_f32(const float* __restrict__ x,
                     const int* __restrict__ ei,
                     const float* __restrict__ W1, const float* __restrict__ b1,
                     const float* __restrict__ W2, const float* __restrict__ b2,
                     float* agg) {
    __shared__ float smem[SMEM_WORDS];
    float* Ax = smem;
    float* Hs = smem;
    float* Wt = smem + AX_WORDS;
    int* scol = (int*)(smem + AX_WORDS + WT_WORDS);

    const int t = threadIdx.x;
    const int base = blockIdx.x * TE;
    {
        const int e = t & 63;
        const int q = t >> 6;
        const int r = ei[base + e];
        const int c = ei[NEDGES + base + e];
        if (t < 64) scol[t] = c;
        const float* srcr = x + (size_t)r * DD;
        const float* srcc = x + (size_t)c * DD;
#pragma unroll
        for (int ci = 0; ci < 16; ++ci) {
            const int k4 = ci * 4 + q;
            float4 v;
            if (k4 < 32) v = *(const float4*)(srcr + k4 * 4);
            else         v = *(const float4*)(srcc + (k4 - 32) * 4);
            *(float4*)(Ax + e * AX_S + k4 * 4) = v;
        }
    }
    const int jg = t & 31;
    const int eg = t >> 5;
    const int j0 = jg * 4;
    const float4 b1v = *(const float4*)(b1 + j0);
    const float4 b2v = *(const float4*)(b2 + j0);
    float acc[8][4];
#pragma unroll
    for (int i = 0; i < 8; ++i)
        acc[i][0] = acc[i][1] = acc[i][2] = acc[i][3] = 0.f;

    for (int kb = 0; kb < 256 / KT; ++kb) {
        __syncthreads();
        {
            const float* src = W1 + kb * KT * DD;
#pragma unroll
            for (int u = 0; u < 2; ++u) {
                const int f4i = u * 256 + t;
                *(float4*)(Wt + f4i * 4) = *(const float4*)(src + f4i * 4);
            }
        }
        __syncthreads();
        float4 Bc[KT];
#pragma unroll
        for (int kk = 0; kk < KT; ++kk)
            Bc[kk] = *(const float4*)(Wt + kk * DD + j0);
#pragma unroll
        for (int i = 0; i < 8; ++i) {
            const float* arow = Ax + (i * 8 + eg) * AX_S + kb * KT;
            float a[KT];
#pragma unroll
            for (int kc = 0; kc < KT / 4; ++kc) {
                const float4 av = *(const float4*)(arow + kc * 4);
                a[kc * 4 + 0] = av.x; a[kc * 4 + 1] = av.y;
                a[kc * 4 + 2] = av.z; a[kc * 4 + 3] = av.w;
            }
#pragma unroll
            for (int kk = 0; kk < KT; ++kk) {
                acc[i][0] = fmaf(a[kk], Bc[kk].x, acc[i][0]);
                acc[i][1] = fmaf(a[kk], Bc[kk].y, acc[i][1]);
                acc[i][2] = fmaf(a[kk], Bc[kk].z, acc[i][2]);
                acc[i][3] = fmaf(a[kk], Bc[kk].w, acc[i][3]);
            }
        }
    }
    __syncthreads();
#pragma unroll
    for (int i = 0; i < 8; ++i) {
        float4 h;
        h.x = fmaxf(acc[i][0] + b1v.x, 0.f);
        h.y = fmaxf(acc[i][1] + b1v.y, 0.f);
        h.z = fmaxf(acc[i][2] + b1v.z, 0.f);
        h.w = fmaxf(acc[i][3] + b1v.w, 0.f);
        *(float4*)(Hs + (i * 8 + eg) * HS_S + j0) = h;
        acc[i][0] = acc[i][1] = acc[i][2] = acc[i][3] = 0.f;
    }
    for (int kb = 0; kb < DD / KT; ++kb) {
        __syncthreads();
        {
            const float* src = W2 + kb * KT * DD;
#pragma unroll
            for (int u = 0; u < 2; ++u) {
                const int f4i = u * 256 + t;
                *(float4*)(Wt + f4i * 4) = *(const float4*)(src + f4i * 4);
            }
        }
        __syncthreads();
        float4 Bc[KT];
#pragma unroll
        for (int kk = 0; kk < KT; ++kk)
            Bc[kk] = *(const float4*)(Wt + kk * DD + j0);
#pragma unroll
        for (int i = 0; i < 8; ++i) {
            const float* arow = Hs + (i * 8 + eg) * HS_S + kb * KT;
            float a[KT];
#pragma unroll
            for (int kc = 0; kc < KT / 4; ++kc) {
                const float4 av = *(const float4*)(arow + kc * 4);
                a[kc * 4 + 0] = av.x; a[kc * 4 + 1] = av.y;
                a[kc * 4 + 2] = av.z; a[kc * 4 + 3] = av.w;
            }
#pragma unroll
            for (int kk = 0; kk < KT; ++kk) {
                acc[i][0] = fmaf(a[kk], Bc[kk].x, acc[i][0]);
                acc[i][1] = fmaf(a[kk], Bc[kk].y, acc[i][1]);
                acc[i][2] = fmaf(a[kk], Bc[kk].z, acc[i][2]);
                acc[i][3] = fmaf(a[kk], Bc[kk].w, acc[i][3]);
            }
        }
    }
#pragma unroll
    for (int i = 0; i < 8; ++i) {
        const int c = scol[i * 8 + eg];
        float* dst = agg + (size_t)c * DD + j0;
        atomicAdd(dst + 0, acc[i][0] + b2v.x);
        atomicAdd(dst + 1, acc[i][1] + b2v.y);
        atomicAdd(dst + 2, acc[i][2] + b2v.z);
        atomicAdd(dst + 3, acc[i][3] + b2v.w);
    }
}

// ---------------------------------------------------------------------------
// Node kernel (unchanged, proven): out = relu(relu([x|agg]@U1+c1)@U2+c2)
// aggout = d_out doubles as agg input; block reads only its own rows first.
__global__ __launch_bounds__(256, 2)
void node_kernel(const float* __restrict__ x,
                 float* aggout,
                 const float* __restrict__ U1, const float* __restrict__ c1,
                 const float* __restrict__ U2, const float* __restrict__ c2) {
    __shared__ float smem[SMEM_WORDS];
    float* Ax = smem;
    float* Hs = smem;
    float* Wt = smem + AX_WORDS;

    const int t = threadIdx.x;
    const int base = blockIdx.x * TE;
    {
        const int e = t & 63;
        const int q = t >> 6;
        const int n = base + e;
        const bool valid = n < NNODES;
        const float* s1 = x + (size_t)n * DD;
        const float* s2 = aggout + (size_t)n * DD;
#pragma unroll
        for (int ci = 0; ci < 16; ++ci) {
            const int k4 = ci * 4 + q;
            float4 v = make_float4(0.f, 0.f, 0.f, 0.f);
            if (valid) {
                if (k4 < 32) v = *(const float4*)(s1 + k4 * 4);
                else         v = *(const float4*)(s2 + (k4 - 32) * 4);
            }
            *(float4*)(Ax + e * AX_S + k4 * 4) = v;
        }
    }
    const int jg = t & 31;
    const int eg = t >> 5;
    const int j0 = jg * 4;
    const float4 b1v = *(const float4*)(c1 + j0);
    const float4 b2v = *(const float4*)(c2 + j0);
    float acc[8][4];
#pragma unroll
    for (int i = 0; i < 8; ++i)
        acc[i][0] = acc[i][1] = acc[i][2] = acc[i][3] = 0.f;

    for (int kb = 0; kb < 256 / KT; ++kb) {
        __syncthreads();
        {
            const float* src = U1 + kb * KT * DD;
#pragma unroll
            for (int u = 0; u < 2; ++u) {
                const int f4i = u * 256 + t;
                *(float4*)(Wt + f4i * 4) = *(const float4*)(src + f4i * 4);
            }
        }
        __syncthreads();
        float4 Bc[KT];
#pragma unroll
        for (int kk = 0; kk < KT; ++kk)
            Bc[kk] = *(const float4*)(Wt + kk * DD + j0);
#pragma unroll
        for (int i = 0; i < 8; ++i) {
            const float* arow = Ax + (i * 8 + eg) * AX_S + kb * KT;
            float a[KT];
#pragma unroll
            for (int kc = 0; kc < KT / 4; ++kc) {
                const float4 av = *(const float4*)(arow + kc * 4);
                a[kc * 4 + 0] = av.x; a[kc * 4 + 1] = av.y;
                a[kc * 4 + 2] = av.z; a[kc * 4 + 3] = av.w;
            }
#pragma unroll
            for (int kk = 0; kk < KT; ++kk) {
                acc[i][0] = fmaf(a[kk], Bc[kk].x, acc[i][0]);
                acc[i][1] = fmaf(a[kk], Bc[kk].y, acc[i][1]);
                acc[i][2] = fmaf(a[kk], Bc[kk].z, acc[i][2]);
                acc[i][3] = fmaf(a[kk], Bc[kk].w, acc[i][3]);
            }
        }
    }
    __syncthreads();
#pragma unroll
    for (int i = 0; i < 8; ++i) {
        float4 h;
        h.x = fmaxf(acc[i][0] + b1v.x, 0.f);
        h.y = fmaxf(acc[i][1] + b1v.y, 0.f);
        h.z = fmaxf(acc[i][2] + b1v.z, 0.f);
        h.w = fmaxf(acc[i][3] + b1v.w, 0.f);
        *(float4*)(Hs + (i * 8 + eg) * HS_S + j0) = h;
        acc[i][0] = acc[i][1] = acc[i][2] = acc[i][3] = 0.f;
    }
    for (int kb = 0; kb < DD / KT; ++kb) {
        __syncthreads();
        {
            const float* src = U2 + kb * KT * DD;
#pragma unroll
            for (int u = 0; u < 2; ++u) {
                const int f4i = u * 256 + t;
                *(float4*)(Wt + f4i * 4) = *(const float4*)(src + f4i * 4);
            }
        }
        __syncthreads();
        float4 Bc[KT];
#pragma unroll
        for (int kk = 0; kk < KT; ++kk)
            Bc[kk] = *(const float4*)(Wt + kk * DD + j0);
#pragma unroll
        for (int i = 0; i < 8; ++i) {
            const float* arow = Hs + (i * 8 + eg) * HS_S + kb * KT;
            float a[KT];
#pragma unroll
            for (int kc = 0; kc < KT / 4; ++kc) {
                const float4 av = *(const float4*)(arow + kc * 4);
                a[kc * 4 + 0] = av.x; a[kc * 4 + 1] = av.y;
                a[kc * 4 + 2] = av.z; a[kc * 4 + 3] = av.w;
            }
#pragma unroll
            for (int kk = 0; kk < KT; ++kk) {
                acc[i][0] = fmaf(a[kk], Bc[kk].x, acc[i][0]);
                acc[i][1] = fmaf(a[kk], Bc[kk].y, acc[i][1]);
                acc[i][2] = fmaf(a[kk], Bc[kk].z, acc[i][2]);
                acc[i][3] = fmaf(a[kk], Bc[kk].w, acc[i][3]);
            }
        }
    }
#pragma unroll
    for (int i = 0; i < 8; ++i) {
        const int n = base + i * 8 + eg;
        if (n < NNODES) {
            float4 o;
            o.x = fmaxf(acc[i][0] + b2v.x, 0.f);
            o.y = fmaxf(acc[i][1] + b2v.y, 0.f);
            o.z = fmaxf(acc[i][2] + b2v.z, 0.f);
            o.w = fmaxf(acc[i][3] + b2v.w, 0.f);
            *(float4*)(aggout + (size_t)n * DD + j0) = o;
        }
    }
}

// ---------------------------------------------------------------------------
extern "C" void kernel_launch(void* const* d_in, const int* in_sizes, int n_in,
                              void* d_out, int out_size, void* d_ws, size_t ws_size,
                              hipStream_t stream) {
    const float* x   = (const float*)d_in[0];
    const int*   ei  = (const int*)d_in[1];
    const float* mW1 = (const float*)d_in[2];
    const float* mb1 = (const float*)d_in[3];
    const float* mW2 = (const float*)d_in[4];
    const float* mb2 = (const float*)d_in[5];
    const float* uW1 = (const float*)d_in[6];
    const float* ub1 = (const float*)d_in[7];
    const float* uW2 = (const float*)d_in[8];
    const float* ub2 = (const float*)d_in[9];
    float* out = (float*)d_out;   // doubles as [N][128] aggregation buffer

    const int n4 = NNODES * DD / 4;
    zero_kernel<<<(n4 + 255) / 256, 256, 0, stream>>>((float4*)out, n4);

    if (ws_size >= WS_NEEDED) {
        ushort_t* xh  = (ushort_t*)((char*)d_ws + XH_OFF);
        ushort_t* xl  = (ushort_t*)((char*)d_ws + XL_OFF);
        ushort_t* w1h = (ushort_t*)((char*)d_ws + W1H_OFF);
        ushort_t* w1l = (ushort_t*)((char*)d_ws + W1L_OFF);
        ushort_t* w2h = (ushort_t*)((char*)d_ws + W2H_OFF);
        ushort_t* w2l = (ushort_t*)((char*)d_ws + W2L_OFF);
        pack_x<<<(NNODES * DD + 255) / 256, 256, 0, stream>>>(x, xh, xl);
        pack_w<<<(W1_ELEMS + 255) / 256, 256, 0, stream>>>(mW1, w1h, w1l, 256);
        pack_w<<<(W2_ELEMS + 255) / 256, 256, 0, stream>>>(mW2, w2h, w2l, 128);
        edge_mfma<<<NEDGES / EB, 256, 0, stream>>>(xh, xl, w1h, w1l, w2h, w2l,
                                                   ei, mb1, mb2, out);
    } else {
        edge_kernel_f32<<<NEDGES / TE, 256, 0, stream>>>(x, ei, mW1, mb1,
                                                         mW2, mb2, out);
    }
    node_kernel<<<(NNODES + TE - 1) / TE, 256, 0, stream>>>(x, out, uW1, ub1,
                                                            uW2, ub2);
}